// Round 1
// baseline (13445.012 us; speedup 1.0000x reference)
//
#include <hip/hip_runtime.h>

#define TT 4
#define BB 2
#define CC 128
#define DD 8
#define HHH 32
#define WWW 32
#define PP (DD*HHH*WWW)        // 8192
#define TSTRIDE (BB*CC*PP)     // 2097152 (per-t stride, same for windowed layout)
#define NWIN 8
#define SSS 1024
#define NHEAD 8
#define HDIM 16
#define THETA 0.7f
#define VTH 1.0f
#define NPERC (TT*BB*PP)       // 65536 elements per channel for BN
#define EPSf 1e-5f

// ---------------- weight prep: fold CDC term into center tap ----------------
__global__ __launch_bounds__(256) void prep_weights(const float* __restrict__ qw,
                                                    float* __restrict__ wmod) {
    int oi = blockIdx.x*256 + threadIdx.x;   // (o,i) pair, 0..16383
    if (oi >= CC*CC) return;
    const float* wp = qw + (size_t)oi*27;
    float kd = 0.f;
    #pragma unroll
    for (int t=0; t<9; t++) kd += wp[t] + wp[18+t];
    float* op = wmod + (size_t)oi*27;
    #pragma unroll
    for (int t=0; t<27; t++) op[t] = wp[t] - ((t==13) ? THETA*kd : 0.f);
}

// ---------------- 3x3x3 conv (CDC folded), 16 o-chan x 4 pos per thread ----
__global__ __launch_bounds__(256) void conv3d_cdc(const float* __restrict__ x,
                                                  const float* __restrict__ wmod,
                                                  float* __restrict__ y) {
    __shared__ float wsm[16*16*27];          // 27.6 KB
    int tid  = threadIdx.x;
    int tile = blockIdx.x;                   // 0..7  (1024 positions)
    int og   = blockIdx.y;                   // 0..7  (16 out channels)
    int tb   = blockIdx.z;                   // 0..7  (t*B+b)
    int obase = og*16;
    const float* xb = x + (size_t)tb*CC*PP;
    float acc[16][4];
    #pragma unroll
    for (int o=0;o<16;o++)
        #pragma unroll
        for (int k=0;k<4;k++) acc[o][k]=0.f;
    int p0[4], d0[4], h0[4], w0[4];
    #pragma unroll
    for (int k=0;k<4;k++){
        p0[k]=tile*1024 + k*256 + tid;
        d0[k]=p0[k]>>10; h0[k]=(p0[k]>>5)&31; w0[k]=p0[k]&31;
    }
    #pragma unroll 1
    for (int ic=0; ic<CC; ic+=16) {
        __syncthreads();
        for (int li=tid; li<16*16*27; li+=256) {
            int oo = li/(16*27); int r = li - oo*(16*27); int ii = r/27; int tp = r - ii*27;
            wsm[li] = wmod[(((size_t)(obase+oo))*CC + (ic+ii))*27 + tp];
        }
        __syncthreads();
        #pragma unroll 1
        for (int ii=0; ii<16; ii++) {
            const float* xc = xb + (size_t)(ic+ii)*PP;
            #pragma unroll
            for (int tp=0; tp<27; tp++) {
                const int dd = tp/9 - 1, dh = (tp/3)%3 - 1, dw = tp%3 - 1;
                float xv[4];
                #pragma unroll
                for (int k=0;k<4;k++){
                    int nd=d0[k]+dd, nh=h0[k]+dh, nw=w0[k]+dw;
                    bool ok = ((unsigned)nd < (unsigned)DD) & ((unsigned)nh < (unsigned)HHH)
                            & ((unsigned)nw < (unsigned)WWW);
                    xv[k] = ok ? xc[(nd<<10)+(nh<<5)+nw] : 0.f;
                }
                #pragma unroll
                for (int oo=0;oo<16;oo++){
                    float wv = wsm[(oo*16+ii)*27+tp];
                    #pragma unroll
                    for (int k=0;k<4;k++) acc[oo][k] += wv*xv[k];
                }
            }
        }
    }
    #pragma unroll
    for (int oo=0;oo<16;oo++)
        #pragma unroll
        for (int k=0;k<4;k++)
            y[((size_t)tb*CC + obase+oo)*PP + p0[k]] = acc[oo][k];
}

// ---------------- pointwise channel-mix GEMM: y[t,b,o,p] = sum_i W[o,i] x[t,b,i,p]
__global__ __launch_bounds__(256) void gemm_cp(const float* __restrict__ xin,
                                               const float* __restrict__ W,
                                               float* __restrict__ y) {
    __shared__ float wl[16*128];             // 8 KB
    int tid  = threadIdx.x;
    int tile = blockIdx.x, og = blockIdx.y, tb = blockIdx.z;
    int obase = og*16;
    for (int li=tid; li<16*128; li+=256) {
        int oo = li>>7; int ii = li&127;
        wl[li] = W[(size_t)(obase+oo)*CC + ii];
    }
    __syncthreads();
    const float* xb = xin + (size_t)tb*CC*PP + tile*1024 + tid;
    float acc[16][4];
    #pragma unroll
    for (int o=0;o<16;o++)
        #pragma unroll
        for (int k=0;k<4;k++) acc[o][k]=0.f;
    #pragma unroll 2
    for (int i=0;i<CC;i++){
        float xv[4];
        #pragma unroll
        for (int k=0;k<4;k++) xv[k] = xb[(size_t)i*PP + k*256];
        #pragma unroll
        for (int oo=0;oo<16;oo++){
            float wv = wl[oo*128+i];
            #pragma unroll
            for (int k=0;k<4;k++) acc[oo][k] += wv*xv[k];
        }
    }
    #pragma unroll
    for (int oo=0;oo<16;oo++)
        #pragma unroll
        for (int k=0;k<4;k++)
            y[((size_t)tb*CC + obase+oo)*PP + tile*1024 + tid + k*256] = acc[oo][k];
}

// ---------------- per-channel BN stats (sum, sumsq), one block per channel ---
__global__ __launch_bounds__(256) void chan_stats(const float* __restrict__ xin,
                                                  float* __restrict__ sum,
                                                  float* __restrict__ sq) {
    int c = blockIdx.x;
    int tid = threadIdx.x;
    float s=0.f, s2=0.f;
    for (int tb=0; tb<TT*BB; tb++) {
        const float* p = xin + ((size_t)tb*CC + c)*PP;
        for (int i=tid; i<PP; i+=256) { float v=p[i]; s+=v; s2+=v*v; }
    }
    __shared__ float ls[256], ls2[256];
    ls[tid]=s; ls2[tid]=s2; __syncthreads();
    for (int off=128; off>0; off>>=1){
        if (tid<off){ ls[tid]+=ls[tid+off]; ls2[tid]+=ls2[tid+off]; }
        __syncthreads();
    }
    if (tid==0){ sum[c]=ls[0]; sq[c]=ls2[0]; }
}

// ---------------- window sums of raw conv output (for region routing) -------
__global__ __launch_bounds__(128) void region_sums(const float* __restrict__ xin,
                                                   float* __restrict__ reg) {
    int blk = blockIdx.x;                    // (b*8+win)*128 + c, 2048 blocks
    int c  = blk & 127;
    int wi = (blk >> 7) & 7;
    int b  = blk >> 10;
    int wd = wi>>2, wh = (wi>>1)&1, wwi = wi&1;
    int tid = threadIdx.x;
    float s = 0.f;
    for (int t=0;t<TT;t++){
        const float* p = xin + ((size_t)(t*BB+b)*CC + c)*PP;
        for (int si=tid; si<SSS; si+=128){
            int ld = si>>8, lh=(si>>4)&15, lw=si&15;
            int d = wd*4+ld, h = wh*16+lh, w = wwi*16+lw;
            s += p[(d<<10)+(h<<5)+w];
        }
    }
    __shared__ float ls[128];
    ls[tid]=s; __syncthreads();
    for (int off=64;off>0;off>>=1){ if(tid<off) ls[tid]+=ls[tid+off]; __syncthreads(); }
    if (tid==0) reg[blk]=ls[0];
}

// ---------------- routing: normalize regions, a_r, top-4 -------------------
__global__ __launch_bounds__(128) void route_topk(const float* __restrict__ qreg,
        const float* __restrict__ kreg,
        const float* __restrict__ qsum, const float* __restrict__ qsq,
        const float* __restrict__ ksum, const float* __restrict__ ksq,
        const float* __restrict__ qg, const float* __restrict__ qb,
        const float* __restrict__ kg, const float* __restrict__ kb,
        int* __restrict__ idxout) {
    __shared__ float qn[16*128], kn[16*128], ar[16*8];
    int tid = threadIdx.x;
    for (int e=tid; e<16*128; e+=128){
        int c = e&127;
        float qm = qsum[c]*(1.f/NPERC);
        float qv = qsq[c]*(1.f/NPERC) - qm*qm;
        float qr = rsqrtf(qv + EPSf);
        qn[e] = (qreg[e]*(1.f/(TT*SSS)) - qm)*qr*qg[c] + qb[c];
        float km = ksum[c]*(1.f/NPERC);
        float kv = ksq[c]*(1.f/NPERC) - km*km;
        float kr = rsqrtf(kv + EPSf);
        kn[e] = (kreg[e]*(1.f/(TT*SSS)) - km)*kr*kg[c] + kb[c];
    }
    __syncthreads();
    {
        int b = tid>>6, w=(tid>>3)&7, v=tid&7;
        float s=0.f;
        for (int c=0;c<128;c++) s += qn[(b*8+w)*128+c]*kn[(b*8+v)*128+c];
        ar[(b*8+w)*8+v] = s * 0.25f;         // HEAD_DIM^-0.5
    }
    __syncthreads();
    if (tid < 16){
        const float* row = &ar[tid*8];
        bool used[8] = {false,false,false,false,false,false,false,false};
        for (int j=0;j<4;j++){
            int best=0; float bv=-3.0e38f;
            for (int v=0; v<8; v++){
                if (!used[v] && row[v] > bv){ bv=row[v]; best=v; }
            }
            used[best]=true;
            idxout[tid*4+j]=best;
        }
    }
}

// ---------------- LIF with fused BN, write spikes in windowed layout --------
__global__ __launch_bounds__(256) void lif_bn_win(const float* __restrict__ xin,
        float* __restrict__ spk,
        const float* __restrict__ sum, const float* __restrict__ sq,
        const float* __restrict__ gamma, const float* __restrict__ beta) {
    int e = blockIdx.x*256 + threadIdx.x;    // over B*C*P = 2097152
    if (e >= BB*CC*PP) return;
    int p = e & (PP-1);
    int c = (e >> 13) & 127;
    int b = e >> 20;
    float mean = sum[c]*(1.f/NPERC);
    float var  = sq[c]*(1.f/NPERC) - mean*mean;
    float sc = rsqrtf(var+EPSf)*gamma[c];
    float sh = beta[c] - mean*sc;
    int d = p>>10, h=(p>>5)&31, w=p&31;
    int wi = ((d>>2)*2 + (h>>4))*2 + (w>>4);
    int si = (((d&3)<<4) + (h&15))*16 + (w&15);
    size_t widx = ((size_t)(b*NWIN+wi)*SSS + si)*CC + c;
    float v=0.f;
    #pragma unroll
    for (int t=0;t<TT;t++){
        float xn = xin[(size_t)t*TSTRIDE + e]*sc + sh;
        v = (v+xn)*0.5f;
        float s = (v>=VTH)?1.f:0.f;
        spk[(size_t)t*TSTRIDE + widx] = s;
        v *= (1.f - s);
    }
}

// ---------------- LIF (no BN), windowed input -> standard-layout spikes -----
__global__ __launch_bounds__(256) void lif_win_std(const float* __restrict__ xin,
                                                   float* __restrict__ outp) {
    int e = blockIdx.x*256 + threadIdx.x;
    if (e >= BB*CC*PP) return;
    int p = e & (PP-1);
    int c = (e >> 13) & 127;
    int b = e >> 20;
    int d = p>>10, h=(p>>5)&31, w=p&31;
    int wi = ((d>>2)*2 + (h>>4))*2 + (w>>4);
    int si = (((d&3)<<4) + (h&15))*16 + (w&15);
    size_t widx = ((size_t)(b*NWIN+wi)*SSS + si)*CC + c;
    float v=0.f;
    #pragma unroll
    for (int t=0;t<TT;t++){
        float xv = xin[(size_t)t*TSTRIDE + widx];
        v = (v+xv)*0.5f;
        float s = (v>=VTH)?1.f:0.f;
        outp[(size_t)t*TSTRIDE + e] = s;
        v *= (1.f - s);
    }
}

// ---------------- window attention with routed k/v + LIF on scores ----------
__global__ __launch_bounds__(256) void attn_kernel(const float* __restrict__ qspk,
        const float* __restrict__ kspk, const float* __restrict__ vspk,
        const int* __restrict__ idx, float* __restrict__ out1) {
    int id = blockIdx.x*256 + threadIdx.x;   // over B*W*S*H = 131072
    if (id >= BB*NWIN*SSS*NHEAD) return;
    int hh = id & 7;
    int s  = (id>>3) & 1023;
    int wi = (id>>13) & 7;
    int b  = id>>16;
    int bw = b*NWIN+wi;
    size_t qbase = ((size_t)bw*SSS + s)*CC + hh*HDIM;
    size_t sbase[4];
    #pragma unroll
    for (int j=0;j<4;j++){
        int src = idx[bw*4+j];
        sbase[j] = ((size_t)(b*NWIN+src)*SSS + s)*CC + hh*HDIM;
    }
    float v=0.f;
    #pragma unroll 1
    for (int t=0;t<TT;t++){
        size_t toff = (size_t)t*TSTRIDE;
        float km[16], vm[16];
        #pragma unroll
        for (int d=0;d<16;d++){ km[d]=0.f; vm[d]=0.f; }
        #pragma unroll
        for (int j=0;j<4;j++){
            const float* kp = kspk+toff+sbase[j];
            const float* vp = vspk+toff+sbase[j];
            #pragma unroll
            for (int d=0; d<16; d++){ km[d]+=kp[d]; vm[d]+=vp[d]; }
        }
        const float* qp = qspk+toff+qbase;
        float att=0.f;
        #pragma unroll
        for (int d=0;d<16;d++) att += qp[d]*km[d];
        att *= 0.25f;                        // mean over top-4
        v = (v+att)*0.5f;
        float sp = (v>=VTH)?1.f:0.f;
        v *= (1.f-sp);
        float spq = sp*0.25f;                // spike * (mean over 4 for v)
        float* op = out1+toff+qbase;
        #pragma unroll
        for (int d=0;d<16;d++) op[d] = spq*vm[d];
    }
}

// ---------------- final BN apply ---------------------------------------------
__global__ __launch_bounds__(256) void bn_apply(const float* __restrict__ xin,
        float* __restrict__ yout,
        const float* __restrict__ sum, const float* __restrict__ sq,
        const float* __restrict__ gamma, const float* __restrict__ beta) {
    size_t i = (size_t)blockIdx.x*256 + threadIdx.x;
    if (i >= (size_t)TT*BB*CC*PP) return;
    int c = (int)((i>>13)&127);
    float mean = sum[c]*(1.f/NPERC);
    float var  = sq[c]*(1.f/NPERC) - mean*mean;
    float sc = rsqrtf(var+EPSf)*gamma[c];
    float sh = beta[c] - mean*sc;
    yout[i] = xin[i]*sc + sh;
}

extern "C" void kernel_launch(void* const* d_in, const int* in_sizes, int n_in,
                              void* d_out, int out_size, void* d_ws, size_t ws_size,
                              hipStream_t stream) {
    const float* x  = (const float*)d_in[0];
    const float* qw = (const float*)d_in[1];
    const float* qg = (const float*)d_in[2];
    const float* qb = (const float*)d_in[3];
    const float* kw = (const float*)d_in[4];
    const float* kg = (const float*)d_in[5];
    const float* kb = (const float*)d_in[6];
    const float* vg = (const float*)d_in[7];
    const float* vb = (const float*)d_in[8];
    const float* pw = (const float*)d_in[9];
    const float* pg = (const float*)d_in[10];
    const float* pb = (const float*)d_in[11];
    float* out = (float*)d_out;
    float* ws  = (float*)d_ws;

    const size_t NEL = (size_t)TT*TSTRIDE;   // 8388608
    float* qconv = ws;
    float* kconv = ws + NEL;
    float* qspk  = ws + 2*NEL;
    float* kspk  = ws + 3*NEL;
    float* vspk  = ws + 4*NEL;
    float* wmod  = ws + 5*NEL;               // 442368 floats
    float* stats = ws + 5*NEL + 442368;
    float *qsum=stats,     *qsq=stats+128,  *ksum=stats+256, *ksq=stats+384,
          *vsum=stats+512, *vsq=stats+640,  *psum=stats+768, *psq=stats+896;
    float* qreg = stats+1024;                // 2048
    float* kreg = qreg+2048;                 // 2048
    int*   idxp = (int*)(kreg+2048);         // 64 ints
    float* out1  = qconv;                    // reuse: qconv dead after lif(q)
    float* out2  = kconv;                    // reuse: kconv dead after lif(k)
    float* pconv = qspk;                     // reuse: qspk dead after attn

    dim3 cg(8,8,8);
    prep_weights<<<64,256,0,stream>>>(qw, wmod);
    conv3d_cdc<<<cg,256,0,stream>>>(x, wmod, qconv);
    gemm_cp<<<cg,256,0,stream>>>(x, kw, kconv);
    chan_stats<<<128,256,0,stream>>>(qconv, qsum, qsq);
    chan_stats<<<128,256,0,stream>>>(kconv, ksum, ksq);
    chan_stats<<<128,256,0,stream>>>(x, vsum, vsq);
    region_sums<<<2048,128,0,stream>>>(qconv, qreg);
    region_sums<<<2048,128,0,stream>>>(kconv, kreg);
    route_topk<<<1,128,0,stream>>>(qreg,kreg,qsum,qsq,ksum,ksq,qg,qb,kg,kb,idxp);
    lif_bn_win<<<8192,256,0,stream>>>(qconv, qspk, qsum,qsq, qg,qb);
    lif_bn_win<<<8192,256,0,stream>>>(kconv, kspk, ksum,ksq, kg,kb);
    lif_bn_win<<<8192,256,0,stream>>>(x,     vspk, vsum,vsq, vg,vb);
    attn_kernel<<<512,256,0,stream>>>(qspk,kspk,vspk,idxp,out1);
    lif_win_std<<<8192,256,0,stream>>>(out1, out2);
    gemm_cp<<<cg,256,0,stream>>>(out2, pw, pconv);
    chan_stats<<<128,256,0,stream>>>(pconv, psum, psq);
    bn_apply<<<32768,256,0,stream>>>(pconv, out, psum, psq, pg, pb);
}

// Round 2
// 1556.666 us; speedup vs baseline: 8.6371x; 8.6371x over previous
//
#include <hip/hip_runtime.h>

#define TT 4
#define BB 2
#define CC 128
#define DD 8
#define HHH 32
#define WWW 32
#define PP (DD*HHH*WWW)        // 8192
#define TSTRIDE (BB*CC*PP)     // 2097152 (per-t stride, same for windowed layout)
#define NWIN 8
#define SSS 1024
#define NHEAD 8
#define HDIM 16
#define THETA 0.7f
#define VTH 1.0f
#define NPERC (TT*BB*PP)       // 65536 elements per channel for BN
#define EPSf 1e-5f

// ---------------- weight prep: fold CDC into center tap + transpose ----------
// Output layout W2[og(8)][ic(128)][tap(27)][oo(16)] so that for fixed
// (og, ic, tap) the 16 output-channel weights are contiguous -> wave-uniform
// s_load_dwordx16 in the conv kernel.
__global__ __launch_bounds__(256) void prep_weights(const float* __restrict__ qw,
                                                    float* __restrict__ W2) {
    int oi = blockIdx.x*256 + threadIdx.x;   // (o,ic) pair, 0..16383
    if (oi >= CC*CC) return;
    int o  = oi >> 7;
    int ic = oi & 127;
    int og = o >> 4, oo = o & 15;
    const float* wp = qw + (size_t)oi*27;
    float kd = 0.f;
    #pragma unroll
    for (int t=0; t<9; t++) kd += wp[t] + wp[18+t];
    #pragma unroll
    for (int t=0; t<27; t++) {
        float v = wp[t] - ((t==13) ? THETA*kd : 0.f);
        W2[(((size_t)og*CC + ic)*27 + t)*16 + oo] = v;
    }
}

// ---------------- 3x3x3 conv (CDC folded), LDS-staged, SGPR weights ----------
// block: 1024 threads = one (tb, d, og); thread = one (h,w); acc[16] o-chans.
// LDS: xs[dz(3)][ii(4)][1024] staged per 4-input-channel chunk + zero guard.
__global__ __launch_bounds__(1024) void conv3d_lds(const float* __restrict__ x,
                                                   const float* __restrict__ W2,
                                                   float* __restrict__ y) {
    __shared__ float xs[15392];              // 12288 data + guard slots
    int tid = threadIdx.x;                   // 0..1023 = h*32+w
    int d   = blockIdx.x;                    // 0..7
    int og  = blockIdx.y;                    // 0..7
    int tb  = blockIdx.z;                    // 0..7
    int h = tid >> 5, w = tid & 31;

    // zero guard slots: reads at 12288 + ii*1024 for ii in 0..3
    if (tid < 4) xs[12288 + tid*1024] = 0.f;

    // precompute 27 tap LDS addresses (ii=0 base); OOB(h,w) -> zero slot
    int addr[27];
    #pragma unroll
    for (int tp=0; tp<27; tp++) {
        int dz = tp/9;
        int dh = (tp/3)%3 - 1, dw = tp%3 - 1;
        int hh = h + dh, ww = w + dw;
        bool ok = ((unsigned)hh < (unsigned)HHH) & ((unsigned)ww < (unsigned)WWW);
        addr[tp] = ok ? (dz*4096 + hh*32 + ww) : 12288;
    }

    float acc[16];
    #pragma unroll
    for (int o=0;o<16;o++) acc[o]=0.f;

    const float* xb = x + (size_t)tb*CC*PP;

    #pragma unroll 1
    for (int ic0=0; ic0<CC; ic0+=4) {
        __syncthreads();
        #pragma unroll
        for (int it=0; it<12; it++) {
            int dz = it >> 2, ii = it & 3;
            int dd = d - 1 + dz;
            float v = 0.f;
            if ((unsigned)dd < (unsigned)DD)
                v = xb[((size_t)(ic0+ii)*DD + dd)*1024 + tid];
            xs[dz*4096 + ii*1024 + tid] = v;
        }
        __syncthreads();
        const float* Wp = W2 + (((size_t)og*CC + ic0)*27)*16;
        #pragma unroll
        for (int ii=0; ii<4; ii++) {
            #pragma unroll
            for (int tp=0; tp<27; tp++) {
                float xv = xs[addr[tp] + ii*1024];
                const float* wv = Wp + (ii*27 + tp)*16;   // wave-uniform -> SGPR
                #pragma unroll
                for (int oo=0; oo<16; oo++)
                    acc[oo] += wv[oo]*xv;
            }
        }
    }
    #pragma unroll
    for (int oo=0; oo<16; oo++)
        y[((size_t)tb*CC + og*16+oo)*PP + d*1024 + tid] = acc[oo];
}

// ---------------- pointwise channel-mix GEMM: y[t,b,o,p] = sum_i W[o,i] x[t,b,i,p]
__global__ __launch_bounds__(256) void gemm_cp(const float* __restrict__ xin,
                                               const float* __restrict__ W,
                                               float* __restrict__ y) {
    __shared__ float wl[16*128];             // 8 KB
    int tid  = threadIdx.x;
    int tile = blockIdx.x, og = blockIdx.y, tb = blockIdx.z;
    int obase = og*16;
    for (int li=tid; li<16*128; li+=256) {
        int oo = li>>7; int ii = li&127;
        wl[li] = W[(size_t)(obase+oo)*CC + ii];
    }
    __syncthreads();
    const float* xb = xin + (size_t)tb*CC*PP + tile*1024 + tid;
    float acc[16][4];
    #pragma unroll
    for (int o=0;o<16;o++)
        #pragma unroll
        for (int k=0;k<4;k++) acc[o][k]=0.f;
    #pragma unroll 2
    for (int i=0;i<CC;i++){
        float xv[4];
        #pragma unroll
        for (int k=0;k<4;k++) xv[k] = xb[(size_t)i*PP + k*256];
        #pragma unroll
        for (int oo=0;oo<16;oo++){
            float wv = wl[oo*128+i];
            #pragma unroll
            for (int k=0;k<4;k++) acc[oo][k] += wv*xv[k];
        }
    }
    #pragma unroll
    for (int oo=0;oo<16;oo++)
        #pragma unroll
        for (int k=0;k<4;k++)
            y[((size_t)tb*CC + obase+oo)*PP + tile*1024 + tid + k*256] = acc[oo][k];
}

// ---------------- per-channel BN stats (sum, sumsq), one block per channel ---
__global__ __launch_bounds__(256) void chan_stats(const float* __restrict__ xin,
                                                  float* __restrict__ sum,
                                                  float* __restrict__ sq) {
    int c = blockIdx.x;
    int tid = threadIdx.x;
    float s=0.f, s2=0.f;
    for (int tb=0; tb<TT*BB; tb++) {
        const float* p = xin + ((size_t)tb*CC + c)*PP;
        for (int i=tid; i<PP; i+=256) { float v=p[i]; s+=v; s2+=v*v; }
    }
    __shared__ float ls[256], ls2[256];
    ls[tid]=s; ls2[tid]=s2; __syncthreads();
    for (int off=128; off>0; off>>=1){
        if (tid<off){ ls[tid]+=ls[tid+off]; ls2[tid]+=ls2[tid+off]; }
        __syncthreads();
    }
    if (tid==0){ sum[c]=ls[0]; sq[c]=ls2[0]; }
}

// ---------------- window sums of raw conv output (for region routing) -------
__global__ __launch_bounds__(128) void region_sums(const float* __restrict__ xin,
                                                   float* __restrict__ reg) {
    int blk = blockIdx.x;                    // (b*8+win)*128 + c, 2048 blocks
    int c  = blk & 127;
    int wi = (blk >> 7) & 7;
    int b  = blk >> 10;
    int wd = wi>>2, wh = (wi>>1)&1, wwi = wi&1;
    int tid = threadIdx.x;
    float s = 0.f;
    for (int t=0;t<TT;t++){
        const float* p = xin + ((size_t)(t*BB+b)*CC + c)*PP;
        for (int si=tid; si<SSS; si+=128){
            int ld = si>>8, lh=(si>>4)&15, lw=si&15;
            int d = wd*4+ld, h = wh*16+lh, w = wwi*16+lw;
            s += p[(d<<10)+(h<<5)+w];
        }
    }
    __shared__ float ls[128];
    ls[tid]=s; __syncthreads();
    for (int off=64;off>0;off>>=1){ if(tid<off) ls[tid]+=ls[tid+off]; __syncthreads(); }
    if (tid==0) reg[blk]=ls[0];
}

// ---------------- routing: normalize regions, a_r, top-4 -------------------
__global__ __launch_bounds__(128) void route_topk(const float* __restrict__ qreg,
        const float* __restrict__ kreg,
        const float* __restrict__ qsum, const float* __restrict__ qsq,
        const float* __restrict__ ksum, const float* __restrict__ ksq,
        const float* __restrict__ qg, const float* __restrict__ qb,
        const float* __restrict__ kg, const float* __restrict__ kb,
        int* __restrict__ idxout) {
    __shared__ float qn[16*128], kn[16*128], ar[16*8];
    int tid = threadIdx.x;
    for (int e=tid; e<16*128; e+=128){
        int c = e&127;
        float qm = qsum[c]*(1.f/NPERC);
        float qv = qsq[c]*(1.f/NPERC) - qm*qm;
        float qr = rsqrtf(qv + EPSf);
        qn[e] = (qreg[e]*(1.f/(TT*SSS)) - qm)*qr*qg[c] + qb[c];
        float km = ksum[c]*(1.f/NPERC);
        float kv = ksq[c]*(1.f/NPERC) - km*km;
        float kr = rsqrtf(kv + EPSf);
        kn[e] = (kreg[e]*(1.f/(TT*SSS)) - km)*kr*kg[c] + kb[c];
    }
    __syncthreads();
    {
        int b = tid>>6, w=(tid>>3)&7, v=tid&7;
        float s=0.f;
        for (int c=0;c<128;c++) s += qn[(b*8+w)*128+c]*kn[(b*8+v)*128+c];
        ar[(b*8+w)*8+v] = s * 0.25f;         // HEAD_DIM^-0.5
    }
    __syncthreads();
    if (tid < 16){
        const float* row = &ar[tid*8];
        bool used[8] = {false,false,false,false,false,false,false,false};
        for (int j=0;j<4;j++){
            int best=0; float bv=-3.0e38f;
            for (int v=0; v<8; v++){
                if (!used[v] && row[v] > bv){ bv=row[v]; best=v; }
            }
            used[best]=true;
            idxout[tid*4+j]=best;
        }
    }
}

// ---------------- LIF with fused BN, write spikes in windowed layout --------
__global__ __launch_bounds__(256) void lif_bn_win(const float* __restrict__ xin,
        float* __restrict__ spk,
        const float* __restrict__ sum, const float* __restrict__ sq,
        const float* __restrict__ gamma, const float* __restrict__ beta) {
    int e = blockIdx.x*256 + threadIdx.x;    // over B*C*P = 2097152
    if (e >= BB*CC*PP) return;
    int p = e & (PP-1);
    int c = (e >> 13) & 127;
    int b = e >> 20;
    float mean = sum[c]*(1.f/NPERC);
    float var  = sq[c]*(1.f/NPERC) - mean*mean;
    float sc = rsqrtf(var+EPSf)*gamma[c];
    float sh = beta[c] - mean*sc;
    int d = p>>10, h=(p>>5)&31, w=p&31;
    int wi = ((d>>2)*2 + (h>>4))*2 + (w>>4);
    int si = (((d&3)<<4) + (h&15))*16 + (w&15);
    size_t widx = ((size_t)(b*NWIN+wi)*SSS + si)*CC + c;
    float v=0.f;
    #pragma unroll
    for (int t=0;t<TT;t++){
        float xn = xin[(size_t)t*TSTRIDE + e]*sc + sh;
        v = (v+xn)*0.5f;
        float s = (v>=VTH)?1.f:0.f;
        spk[(size_t)t*TSTRIDE + widx] = s;
        v *= (1.f - s);
    }
}

// ---------------- LIF (no BN), windowed input -> standard-layout spikes -----
__global__ __launch_bounds__(256) void lif_win_std(const float* __restrict__ xin,
                                                   float* __restrict__ outp) {
    int e = blockIdx.x*256 + threadIdx.x;
    if (e >= BB*CC*PP) return;
    int p = e & (PP-1);
    int c = (e >> 13) & 127;
    int b = e >> 20;
    int d = p>>10, h=(p>>5)&31, w=p&31;
    int wi = ((d>>2)*2 + (h>>4))*2 + (w>>4);
    int si = (((d&3)<<4) + (h&15))*16 + (w&15);
    size_t widx = ((size_t)(b*NWIN+wi)*SSS + si)*CC + c;
    float v=0.f;
    #pragma unroll
    for (int t=0;t<TT;t++){
        float xv = xin[(size_t)t*TSTRIDE + widx];
        v = (v+xv)*0.5f;
        float s = (v>=VTH)?1.f:0.f;
        outp[(size_t)t*TSTRIDE + e] = s;
        v *= (1.f - s);
    }
}

// ---------------- window attention with routed k/v + LIF on scores ----------
__global__ __launch_bounds__(256) void attn_kernel(const float* __restrict__ qspk,
        const float* __restrict__ kspk, const float* __restrict__ vspk,
        const int* __restrict__ idx, float* __restrict__ out1) {
    int id = blockIdx.x*256 + threadIdx.x;   // over B*W*S*H = 131072
    if (id >= BB*NWIN*SSS*NHEAD) return;
    int hh = id & 7;
    int s  = (id>>3) & 1023;
    int wi = (id>>13) & 7;
    int b  = id>>16;
    int bw = b*NWIN+wi;
    size_t qbase = ((size_t)bw*SSS + s)*CC + hh*HDIM;
    size_t sbase[4];
    #pragma unroll
    for (int j=0;j<4;j++){
        int src = idx[bw*4+j];
        sbase[j] = ((size_t)(b*NWIN+src)*SSS + s)*CC + hh*HDIM;
    }
    float v=0.f;
    #pragma unroll 1
    for (int t=0;t<TT;t++){
        size_t toff = (size_t)t*TSTRIDE;
        float km[16], vm[16];
        #pragma unroll
        for (int d=0;d<16;d++){ km[d]=0.f; vm[d]=0.f; }
        #pragma unroll
        for (int j=0;j<4;j++){
            const float* kp = kspk+toff+sbase[j];
            const float* vp = vspk+toff+sbase[j];
            #pragma unroll
            for (int d=0; d<16; d++){ km[d]+=kp[d]; vm[d]+=vp[d]; }
        }
        const float* qp = qspk+toff+qbase;
        float att=0.f;
        #pragma unroll
        for (int d=0;d<16;d++) att += qp[d]*km[d];
        att *= 0.25f;                        // mean over top-4
        v = (v+att)*0.5f;
        float sp = (v>=VTH)?1.f:0.f;
        v *= (1.f-sp);
        float spq = sp*0.25f;                // spike * (mean over 4 for v)
        float* op = out1+toff+qbase;
        #pragma unroll
        for (int d=0;d<16;d++) op[d] = spq*vm[d];
    }
}

// ---------------- final BN apply ---------------------------------------------
__global__ __launch_bounds__(256) void bn_apply(const float* __restrict__ xin,
        float* __restrict__ yout,
        const float* __restrict__ sum, const float* __restrict__ sq,
        const float* __restrict__ gamma, const float* __restrict__ beta) {
    size_t i = (size_t)blockIdx.x*256 + threadIdx.x;
    if (i >= (size_t)TT*BB*CC*PP) return;
    int c = (int)((i>>13)&127);
    float mean = sum[c]*(1.f/NPERC);
    float var  = sq[c]*(1.f/NPERC) - mean*mean;
    float sc = rsqrtf(var+EPSf)*gamma[c];
    float sh = beta[c] - mean*sc;
    yout[i] = xin[i]*sc + sh;
}

extern "C" void kernel_launch(void* const* d_in, const int* in_sizes, int n_in,
                              void* d_out, int out_size, void* d_ws, size_t ws_size,
                              hipStream_t stream) {
    const float* x  = (const float*)d_in[0];
    const float* qw = (const float*)d_in[1];
    const float* qg = (const float*)d_in[2];
    const float* qb = (const float*)d_in[3];
    const float* kw = (const float*)d_in[4];
    const float* kg = (const float*)d_in[5];
    const float* kb = (const float*)d_in[6];
    const float* vg = (const float*)d_in[7];
    const float* vb = (const float*)d_in[8];
    const float* pw = (const float*)d_in[9];
    const float* pg = (const float*)d_in[10];
    const float* pb = (const float*)d_in[11];
    float* out = (float*)d_out;
    float* ws  = (float*)d_ws;

    const size_t NEL = (size_t)TT*TSTRIDE;   // 8388608
    float* qconv = ws;
    float* kconv = ws + NEL;
    float* qspk  = ws + 2*NEL;
    float* kspk  = ws + 3*NEL;
    float* vspk  = ws + 4*NEL;
    float* wmod  = ws + 5*NEL;               // 442368 floats (transposed layout)
    float* stats = ws + 5*NEL + 442368;
    float *qsum=stats,     *qsq=stats+128,  *ksum=stats+256, *ksq=stats+384,
          *vsum=stats+512, *vsq=stats+640,  *psum=stats+768, *psq=stats+896;
    float* qreg = stats+1024;                // 2048
    float* kreg = qreg+2048;                 // 2048
    int*   idxp = (int*)(kreg+2048);         // 64 ints
    float* out1  = qconv;                    // reuse: qconv dead after lif(q)
    float* out2  = kconv;                    // reuse: kconv dead after lif(k)
    float* pconv = qspk;                     // reuse: qspk dead after attn

    dim3 cg(8,8,8);
    prep_weights<<<64,256,0,stream>>>(qw, wmod);
    conv3d_lds<<<cg,1024,0,stream>>>(x, wmod, qconv);
    gemm_cp<<<cg,256,0,stream>>>(x, kw, kconv);
    chan_stats<<<128,256,0,stream>>>(qconv, qsum, qsq);
    chan_stats<<<128,256,0,stream>>>(kconv, ksum, ksq);
    chan_stats<<<128,256,0,stream>>>(x, vsum, vsq);
    region_sums<<<2048,128,0,stream>>>(qconv, qreg);
    region_sums<<<2048,128,0,stream>>>(kconv, kreg);
    route_topk<<<1,128,0,stream>>>(qreg,kreg,qsum,qsq,ksum,ksq,qg,qb,kg,kb,idxp);
    lif_bn_win<<<8192,256,0,stream>>>(qconv, qspk, qsum,qsq, qg,qb);
    lif_bn_win<<<8192,256,0,stream>>>(kconv, kspk, ksum,ksq, kg,kb);
    lif_bn_win<<<8192,256,0,stream>>>(x,     vspk, vsum,vsq, vg,vb);
    attn_kernel<<<512,256,0,stream>>>(qspk,kspk,vspk,idxp,out1);
    lif_win_std<<<8192,256,0,stream>>>(out1, out2);
    gemm_cp<<<cg,256,0,stream>>>(out2, pw, pconv);
    chan_stats<<<128,256,0,stream>>>(pconv, psum, psq);
    bn_apply<<<32768,256,0,stream>>>(pconv, out, psum, psq, pg, pb);
}

// Round 3
// 1052.664 us; speedup vs baseline: 12.7724x; 1.4788x over previous
//
#include <hip/hip_runtime.h>

#define TT 4
#define BB 2
#define CC 128
#define DD 8
#define HHH 32
#define WWW 32
#define PP (DD*HHH*WWW)        // 8192
#define TSTRIDE (BB*CC*PP)     // 2097152
#define NWIN 8
#define SSS 1024
#define NHEAD 8
#define HDIM 16
#define THETA 0.7f
#define VTH 1.0f
#define NPERC (TT*BB*PP)       // 65536 elements per channel for BN
#define EPSf 1e-5f

#define XPAD_CSTRIDE (10*1024)           // 10 d-slices per channel
#define XPAD_TBSTRIDE (CC*XPAD_CSTRIDE)  // per (t,b)
#define XPAD_TOTAL ((size_t)TT*BB*XPAD_TBSTRIDE)   // 10485760

// ---------------- weight prep: fold CDC into center tap + transpose ----------
// W2[og(8)][ic(128)][tap(27)][oo(16)]
__global__ __launch_bounds__(256) void prep_weights(const float* __restrict__ qw,
                                                    float* __restrict__ W2) {
    int oi = blockIdx.x*256 + threadIdx.x;   // (o,ic) pair
    if (oi >= CC*CC) return;
    int o  = oi >> 7;
    int ic = oi & 127;
    int og = o >> 4, oo = o & 15;
    const float* wp = qw + (size_t)oi*27;
    float kd = 0.f;
    #pragma unroll
    for (int t=0; t<9; t++) kd += wp[t] + wp[18+t];
    #pragma unroll
    for (int t=0; t<27; t++) {
        float v = wp[t] - ((t==13) ? THETA*kd : 0.f);
        W2[(((size_t)og*CC + ic)*27 + t)*16 + oo] = v;
    }
}

// ---------------- pad x along d: [tb][c][10][1024], zeros at dp=0,9 ----------
__global__ __launch_bounds__(512) void pad_x(const float* __restrict__ x,
                                             float* __restrict__ xp) {
    size_t i = (size_t)blockIdx.x*512 + threadIdx.x;
    if (i >= XPAD_TOTAL) return;
    int pos = (int)(i % (size_t)XPAD_CSTRIDE);
    size_t tbc = i / (size_t)XPAD_CSTRIDE;
    int dp = pos >> 10;
    float v = 0.f;
    if (dp >= 1 && dp <= 8)
        v = x[tbc*PP + (size_t)(dp-1)*1024 + (pos & 1023)];
    xp[i] = v;
}

// ---------------- 3x3x3 conv (CDC folded): implicit GEMM, no LDS ------------
// thread = one (h,w) position at fixed (tb,d), 16 out-channels.
__global__ __launch_bounds__(512) void conv3d_ig(const float* __restrict__ xp,
                                                 const float* __restrict__ W2,
                                                 float* __restrict__ y) {
    int tid  = threadIdx.x;
    int d    = blockIdx.x >> 1;
    int half = blockIdx.x & 1;
    int og   = blockIdx.y;
    int tb   = blockIdx.z;
    int p = half*512 + tid;
    int h = p >> 5, w = p & 31;

    float mh0 = (h>0)?1.f:0.f, mh2 = (h<31)?1.f:0.f;
    float mw0 = (w>0)?1.f:0.f, mw2 = (w<31)?1.f:0.f;
    float msk[9];
    msk[0]=mh0*mw0; msk[1]=mh0; msk[2]=mh0*mw2;
    msk[3]=mw0;     msk[4]=1.f; msk[5]=mw2;
    msk[6]=mh2*mw0; msk[7]=mh2; msk[8]=mh2*mw2;

    // base at pad-slice dp=d (tap dz reads dp=d+dz = real d-1+dz)
    const float* xb = xp + (size_t)tb*XPAD_TBSTRIDE + (size_t)d*1024 + p;
    const float* Wp = W2 + (size_t)og*CC*27*16;

    float acc[16];
    #pragma unroll
    for (int oo=0; oo<16; oo++) acc[oo]=0.f;

    #pragma unroll 1
    for (int ic=0; ic<CC; ic++) {
        const float* xc = xb + (size_t)ic*XPAD_CSTRIDE;
        const float* wr = Wp + ic*(27*16);
        #pragma unroll
        for (int dz=0; dz<3; dz++) {
            float xv[9];
            #pragma unroll
            for (int t9=0; t9<9; t9++) {
                int dh = t9/3 - 1, dw = t9%3 - 1;
                xv[t9] = xc[dz*1024 + dh*32 + dw] * msk[t9];
            }
            #pragma unroll
            for (int t9=0; t9<9; t9++) {
                const float* wv = wr + (dz*9+t9)*16;   // wave-uniform -> s_load
                #pragma unroll
                for (int oo=0; oo<16; oo++)
                    acc[oo] += wv[oo]*xv[t9];
            }
        }
    }
    #pragma unroll
    for (int oo=0; oo<16; oo++)
        y[((size_t)tb*CC + og*16+oo)*PP + d*1024 + p] = acc[oo];
}

// ---------------- pointwise channel-mix GEMM ---------------------------------
__global__ __launch_bounds__(256) void gemm_cp(const float* __restrict__ xin,
                                               const float* __restrict__ W,
                                               float* __restrict__ y) {
    __shared__ float wl[16*128];
    int tid  = threadIdx.x;
    int tile = blockIdx.x, og = blockIdx.y, tb = blockIdx.z;
    int obase = og*16;
    for (int li=tid; li<16*128; li+=256) {
        int oo = li>>7; int ii = li&127;
        wl[li] = W[(size_t)(obase+oo)*CC + ii];
    }
    __syncthreads();
    const float* xb = xin + (size_t)tb*CC*PP + tile*1024 + tid;
    float acc[16][4];
    #pragma unroll
    for (int o=0;o<16;o++)
        #pragma unroll
        for (int k=0;k<4;k++) acc[o][k]=0.f;
    #pragma unroll 2
    for (int i=0;i<CC;i++){
        float xv[4];
        #pragma unroll
        for (int k=0;k<4;k++) xv[k] = xb[(size_t)i*PP + k*256];
        #pragma unroll
        for (int oo=0;oo<16;oo++){
            float wv = wl[oo*128+i];
            #pragma unroll
            for (int k=0;k<4;k++) acc[oo][k] += wv*xv[k];
        }
    }
    #pragma unroll
    for (int oo=0;oo<16;oo++)
        #pragma unroll
        for (int k=0;k<4;k++)
            y[((size_t)tb*CC + obase+oo)*PP + tile*1024 + tid + k*256] = acc[oo][k];
}

// ---------------- per-(src,b,win,c) sum & sumsq partials ---------------------
// blk: src(3) x b(2) x wi(8) x c(128) = 6144 blocks
__global__ __launch_bounds__(128) void win_stats(const float* __restrict__ q,
        const float* __restrict__ k, const float* __restrict__ x,
        float* __restrict__ rsum, float* __restrict__ rsq) {
    int blk = blockIdx.x;
    int src = blk >> 11;
    int r   = blk & 2047;
    const float* base = (src==0) ? q : ((src==1) ? k : x);
    int c  = r & 127;
    int wi = (r >> 7) & 7;
    int b  = r >> 10;
    int wd = wi>>2, wh = (wi>>1)&1, ww = wi&1;
    int tid = threadIdx.x;
    float s=0.f, s2=0.f;
    for (int t=0;t<TT;t++){
        const float* p = base + ((size_t)(t*BB+b)*CC + c)*PP;
        for (int si=tid; si<SSS; si+=128){
            int ld = si>>8, lh=(si>>4)&15, lw=si&15;
            float v = p[((wd*4+ld)<<10) + ((wh*16+lh)<<5) + (ww*16+lw)];
            s += v; s2 += v*v;
        }
    }
    __shared__ float ls[128], ls2[128];
    ls[tid]=s; ls2[tid]=s2; __syncthreads();
    for (int off=64;off>0;off>>=1){
        if(tid<off){ ls[tid]+=ls[tid+off]; ls2[tid]+=ls2[tid+off]; }
        __syncthreads();
    }
    if (tid==0){ rsum[blk]=ls[0]; rsq[blk]=ls2[0]; }
}

// ---------------- finalize per-channel stats for q,k,v ----------------------
// sums layout: [src*256 + c] = sum, [src*256 + 128 + c] = sumsq
__global__ __launch_bounds__(384) void stats_fin(const float* __restrict__ rsum,
        const float* __restrict__ rsq, float* __restrict__ sums) {
    int tid = threadIdx.x;
    int src = tid >> 7, c = tid & 127;
    float s=0.f, s2=0.f;
    for (int bw=0; bw<16; bw++){
        int idx = src*2048 + bw*128 + c;
        s  += rsum[idx];
        s2 += rsq[idx];
    }
    sums[src*256 + c]       = s;
    sums[src*256 + 128 + c] = s2;
}

// ---------------- routing: normalize regions, a_r, top-4 --------------------
__global__ __launch_bounds__(128) void route_topk(const float* __restrict__ qreg,
        const float* __restrict__ kreg,
        const float* __restrict__ qsum, const float* __restrict__ qsq,
        const float* __restrict__ ksum, const float* __restrict__ ksq,
        const float* __restrict__ qg, const float* __restrict__ qb,
        const float* __restrict__ kg, const float* __restrict__ kb,
        int* __restrict__ idxout) {
    __shared__ float qn[16*128], kn[16*128], ar[16*8];
    int tid = threadIdx.x;
    for (int e=tid; e<16*128; e+=128){
        int c = e&127;
        float qm = qsum[c]*(1.f/NPERC);
        float qv = qsq[c]*(1.f/NPERC) - qm*qm;
        float qr = rsqrtf(qv + EPSf);
        qn[e] = (qreg[e]*(1.f/(TT*SSS)) - qm)*qr*qg[c] + qb[c];
        float km = ksum[c]*(1.f/NPERC);
        float kv = ksq[c]*(1.f/NPERC) - km*km;
        float kr = rsqrtf(kv + EPSf);
        kn[e] = (kreg[e]*(1.f/(TT*SSS)) - km)*kr*kg[c] + kb[c];
    }
    __syncthreads();
    {
        int b = tid>>6, w=(tid>>3)&7, v=tid&7;
        float s=0.f;
        for (int c=0;c<128;c++) s += qn[(b*8+w)*128+c]*kn[(b*8+v)*128+c];
        ar[(b*8+w)*8+v] = s * 0.25f;
    }
    __syncthreads();
    if (tid < 16){
        const float* row = &ar[tid*8];
        bool used[8] = {false,false,false,false,false,false,false,false};
        for (int j=0;j<4;j++){
            int best=0; float bv=-3.0e38f;
            for (int v=0; v<8; v++){
                if (!used[v] && row[v] > bv){ bv=row[v]; best=v; }
            }
            used[best]=true;
            idxout[tid*4+j]=best;
        }
    }
}

// ---------------- LIF with fused BN, spikes in c-major windowed layout ------
// spk[bw][c][si] : widx = ((bw*CC + c)*SSS + si)
__global__ __launch_bounds__(256) void lif_bn_win(const float* __restrict__ xin,
        float* __restrict__ spk,
        const float* __restrict__ sum, const float* __restrict__ sq,
        const float* __restrict__ gamma, const float* __restrict__ beta) {
    int e = blockIdx.x*256 + threadIdx.x;
    if (e >= BB*CC*PP) return;
    int p = e & (PP-1);
    int c = (e >> 13) & 127;
    int b = e >> 20;
    float mean = sum[c]*(1.f/NPERC);
    float var  = sq[c]*(1.f/NPERC) - mean*mean;
    float sc = rsqrtf(var+EPSf)*gamma[c];
    float sh = beta[c] - mean*sc;
    int d = p>>10, h=(p>>5)&31, w=p&31;
    int wi = ((d>>2)*2 + (h>>4))*2 + (w>>4);
    int si = (((d&3)<<4) + (h&15))*16 + (w&15);
    size_t widx = ((size_t)(b*NWIN+wi)*CC + c)*SSS + si;
    float v=0.f;
    #pragma unroll
    for (int t=0;t<TT;t++){
        float xn = xin[(size_t)t*TSTRIDE + e]*sc + sh;
        v = (v+xn)*0.5f;
        float s = (v>=VTH)?1.f:0.f;
        spk[(size_t)t*TSTRIDE + widx] = s;
        v *= (1.f - s);
    }
}

// ---------------- LIF (no BN): c-major windowed -> standard layout ----------
__global__ __launch_bounds__(256) void lif_win_std(const float* __restrict__ xin,
                                                   float* __restrict__ outp) {
    int e = blockIdx.x*256 + threadIdx.x;
    if (e >= BB*CC*PP) return;
    int p = e & (PP-1);
    int c = (e >> 13) & 127;
    int b = e >> 20;
    int d = p>>10, h=(p>>5)&31, w=p&31;
    int wi = ((d>>2)*2 + (h>>4))*2 + (w>>4);
    int si = (((d&3)<<4) + (h&15))*16 + (w&15);
    size_t widx = ((size_t)(b*NWIN+wi)*CC + c)*SSS + si;
    float v=0.f;
    #pragma unroll
    for (int t=0;t<TT;t++){
        float xv = xin[(size_t)t*TSTRIDE + widx];
        v = (v+xv)*0.5f;
        float s = (v>=VTH)?1.f:0.f;
        outp[(size_t)t*TSTRIDE + e] = s;
        v *= (1.f - s);
    }
}

// ---------------- window attention, c-major layout, s = lane-fastest --------
__global__ __launch_bounds__(256) void attn_kernel(const float* __restrict__ qspk,
        const float* __restrict__ kspk, const float* __restrict__ vspk,
        const int* __restrict__ idx, float* __restrict__ out1) {
    int id = blockIdx.x*256 + threadIdx.x;   // B*W*H*S = 131072
    if (id >= BB*NWIN*NHEAD*SSS) return;
    int s  = id & 1023;
    int hh = (id>>10) & 7;
    int wi = (id>>13) & 7;
    int b  = id>>16;
    int bw = b*NWIN+wi;
    size_t qbase = ((size_t)bw*CC + hh*HDIM)*SSS + s;
    size_t sbase[4];
    #pragma unroll
    for (int j=0;j<4;j++){
        int src = idx[bw*4+j];
        sbase[j] = ((size_t)(b*NWIN+src)*CC + hh*HDIM)*SSS + s;
    }
    float v=0.f;
    #pragma unroll 1
    for (int t=0;t<TT;t++){
        size_t toff = (size_t)t*TSTRIDE;
        float km[16], vm[16];
        #pragma unroll
        for (int d=0;d<16;d++){ km[d]=0.f; vm[d]=0.f; }
        #pragma unroll
        for (int j=0;j<4;j++){
            const float* kp = kspk+toff+sbase[j];
            const float* vp = vspk+toff+sbase[j];
            #pragma unroll
            for (int d=0; d<16; d++){
                km[d] += kp[(size_t)d*SSS];
                vm[d] += vp[(size_t)d*SSS];
            }
        }
        const float* qp = qspk+toff+qbase;
        float att=0.f;
        #pragma unroll
        for (int d=0;d<16;d++) att += qp[(size_t)d*SSS]*km[d];
        att *= 0.25f;
        v = (v+att)*0.5f;
        float sp = (v>=VTH)?1.f:0.f;
        v *= (1.f-sp);
        float spq = sp*0.25f;
        float* op = out1+toff+qbase;
        #pragma unroll
        for (int d=0;d<16;d++) op[(size_t)d*SSS] = spq*vm[d];
    }
}

// ---------------- p-stats: partials over (tb,c), then finalize ---------------
__global__ __launch_bounds__(256) void pstats_part(const float* __restrict__ xin,
        float* __restrict__ part_sum, float* __restrict__ part_sq) {
    int blk = blockIdx.x;                    // tb*128 + c
    int c = blk & 127, tb = blk >> 7;
    int tid = threadIdx.x;
    const float* p = xin + ((size_t)tb*CC + c)*PP;
    float s=0.f, s2=0.f;
    for (int i=tid; i<PP; i+=256){ float v=p[i]; s+=v; s2+=v*v; }
    __shared__ float ls[256], ls2[256];
    ls[tid]=s; ls2[tid]=s2; __syncthreads();
    for (int off=128; off>0; off>>=1){
        if (tid<off){ ls[tid]+=ls[tid+off]; ls2[tid]+=ls2[tid+off]; }
        __syncthreads();
    }
    if (tid==0){ part_sum[blk]=ls[0]; part_sq[blk]=ls2[0]; }
}

__global__ __launch_bounds__(128) void pstats_fin(const float* __restrict__ part_sum,
        const float* __restrict__ part_sq, float* __restrict__ sum,
        float* __restrict__ sq) {
    int c = threadIdx.x;
    float s=0.f, s2=0.f;
    for (int tb=0; tb<8; tb++){
        s  += part_sum[tb*128+c];
        s2 += part_sq[tb*128+c];
    }
    sum[c]=s; sq[c]=s2;
}

// ---------------- final BN apply ---------------------------------------------
__global__ __launch_bounds__(256) void bn_apply(const float* __restrict__ xin,
        float* __restrict__ yout,
        const float* __restrict__ sum, const float* __restrict__ sq,
        const float* __restrict__ gamma, const float* __restrict__ beta) {
    size_t i = (size_t)blockIdx.x*256 + threadIdx.x;
    if (i >= (size_t)TT*BB*CC*PP) return;
    int c = (int)((i>>13)&127);
    float mean = sum[c]*(1.f/NPERC);
    float var  = sq[c]*(1.f/NPERC) - mean*mean;
    float sc = rsqrtf(var+EPSf)*gamma[c];
    float sh = beta[c] - mean*sc;
    yout[i] = xin[i]*sc + sh;
}

extern "C" void kernel_launch(void* const* d_in, const int* in_sizes, int n_in,
                              void* d_out, int out_size, void* d_ws, size_t ws_size,
                              hipStream_t stream) {
    const float* x  = (const float*)d_in[0];
    const float* qw = (const float*)d_in[1];
    const float* qg = (const float*)d_in[2];
    const float* qb = (const float*)d_in[3];
    const float* kw = (const float*)d_in[4];
    const float* kg = (const float*)d_in[5];
    const float* kb = (const float*)d_in[6];
    const float* vg = (const float*)d_in[7];
    const float* vb = (const float*)d_in[8];
    const float* pw = (const float*)d_in[9];
    const float* pg = (const float*)d_in[10];
    const float* pb = (const float*)d_in[11];
    float* out = (float*)d_out;
    float* ws  = (float*)d_ws;

    const size_t NEL = (size_t)TT*TSTRIDE;   // 8388608
    float* qconv = ws;
    float* kconv = ws + NEL;
    float* qspk  = ws + 2*NEL;
    float* kspk  = ws + 3*NEL;
    float* vspk  = ws + 4*NEL;
    float* wmod  = ws + 5*NEL;               // 442368 floats
    float* stats = ws + 5*NEL + 442368;      // 3*256 q/k/v sums + 256 p
    float *qsum=stats,     *qsq=stats+128,  *ksum=stats+256, *ksq=stats+384,
          *vsum=stats+512, *vsq=stats+640,  *psum=stats+768, *psq=stats+896;
    float* rsum = stats + 1024;              // 6144
    float* rsq  = rsum + 6144;               // 6144
    float* ppart_sum = rsq + 6144;           // 1024
    float* ppart_sq  = ppart_sum + 1024;     // 1024
    int*   idxp = (int*)(ppart_sq + 1024);   // 64 ints

    // reuse (lifetimes): xpad lives in qspk..(+10.49M) until conv done;
    // out1 = qconv (dead after lif_bn_win(q)); out2 = kconv; pconv = qspk.
    float* xpad = qspk;
    float* out1 = qconv;
    float* out2 = kconv;
    float* pconv = qspk;

    prep_weights<<<64,256,0,stream>>>(qw, wmod);
    pad_x<<<(int)((XPAD_TOTAL+511)/512),512,0,stream>>>(x, xpad);
    {
        dim3 cvg(16,8,8);
        conv3d_ig<<<cvg,512,0,stream>>>(xpad, wmod, qconv);
    }
    {
        dim3 cg(8,8,8);
        gemm_cp<<<cg,256,0,stream>>>(x, kw, kconv);
    }
    win_stats<<<6144,128,0,stream>>>(qconv, kconv, x, rsum, rsq);
    stats_fin<<<1,384,0,stream>>>(rsum, rsq, stats);
    route_topk<<<1,128,0,stream>>>(rsum, rsum+2048, qsum,qsq,ksum,ksq,qg,qb,kg,kb,idxp);
    lif_bn_win<<<8192,256,0,stream>>>(qconv, qspk, qsum,qsq, qg,qb);
    lif_bn_win<<<8192,256,0,stream>>>(kconv, kspk, ksum,ksq, kg,kb);
    lif_bn_win<<<8192,256,0,stream>>>(x,     vspk, vsum,vsq, vg,vb);
    attn_kernel<<<512,256,0,stream>>>(qspk,kspk,vspk,idxp,out1);
    lif_win_std<<<8192,256,0,stream>>>(out1, out2);
    {
        dim3 cg(8,8,8);
        gemm_cp<<<cg,256,0,stream>>>(out2, pw, pconv);
    }
    pstats_part<<<1024,256,0,stream>>>(pconv, ppart_sum, ppart_sq);
    pstats_fin<<<1,128,0,stream>>>(ppart_sum, ppart_sq, psum, psq);
    bn_apply<<<32768,256,0,stream>>>(pconv, out, psum, psq, pg, pb);
}